// Round 4
// baseline (5611.914 us; speedup 1.0000x reference)
//
#include <hip/hip_runtime.h>
#include <cstdint>
#include <cstddef>

#define D_   4096
#define H_   32
#define HD_  128
#define F_   11008
#define L_   2
#define R_   64
#define BB   2
#define SS   1024
#define TOK  (BB*SS)
#define EPS_ 1e-5f

typedef __attribute__((ext_vector_type(8))) short          s16x8;
typedef __attribute__((ext_vector_type(4))) float          fx4;
typedef __attribute__((ext_vector_type(4))) unsigned short u16x4t;

__device__ __forceinline__ unsigned short f2bf(float f) {
  union { float f; unsigned u; } x; x.f = f;
  unsigned r = (x.u + 0x7FFFu + ((x.u >> 16) & 1u)) >> 16;
  return (unsigned short)r;
}

// ---------------------------------------------------------------------------
// Embedding gather
// ---------------------------------------------------------------------------
__global__ void k_embed(const int* __restrict__ ids, const float* __restrict__ emb,
                        float* __restrict__ x) {
  const int tok = blockIdx.x, tid = threadIdx.x;
  const int id = ids[tok];
  const float* s = emb + (size_t)id * D_;
  float* d = x + (size_t)tok * D_;
#pragma unroll
  for (int i = 0; i < 4; ++i)
    *(fx4*)(d + i * 1024 + tid * 4) = *(const fx4*)(s + i * 1024 + tid * 4);
}

// ---------------------------------------------------------------------------
// RMSNorm row -> bf16
// ---------------------------------------------------------------------------
__global__ __launch_bounds__(256) void k_rmsnorm(const float* __restrict__ x,
                                                 const float* __restrict__ w,
                                                 unsigned short* __restrict__ out) {
  const int row = blockIdx.x, tid = threadIdx.x;
  const float* xr = x + (size_t)row * D_;
  fx4 v[4];
  float ss = 0.f;
#pragma unroll
  for (int i = 0; i < 4; ++i) {
    v[i] = *(const fx4*)(xr + i * 1024 + tid * 4);
    ss += v[i][0]*v[i][0] + v[i][1]*v[i][1] + v[i][2]*v[i][2] + v[i][3]*v[i][3];
  }
#pragma unroll
  for (int off = 32; off > 0; off >>= 1) ss += __shfl_down(ss, off);
  __shared__ float red[4];
  if ((tid & 63) == 0) red[tid >> 6] = ss;
  __syncthreads();
  const float sc = rsqrtf((red[0] + red[1] + red[2] + red[3]) * (1.f / D_) + EPS_);
  unsigned short* orow = out + (size_t)row * D_;
#pragma unroll
  for (int i = 0; i < 4; ++i) {
    fx4 wv = *(const fx4*)(w + i * 1024 + tid * 4);
    u16x4t pk;
    pk.x = f2bf(v[i][0] * sc * wv[0]);
    pk.y = f2bf(v[i][1] * sc * wv[1]);
    pk.z = f2bf(v[i][2] * sc * wv[2]);
    pk.w = f2bf(v[i][3] * sc * wv[3]);
    *(u16x4t*)(orow + i * 1024 + tid * 4) = pk;
  }
}

// ---------------------------------------------------------------------------
// LoRA-merged weight: Wm[n,k] = bf16(W[n,k] + 0.25 * sum_r Bl[n,r]*Al[r,k])
// ---------------------------------------------------------------------------
__global__ __launch_bounds__(256) void k_merge(const float* __restrict__ W,
                                               const float* __restrict__ Al,   // [R,Kd]
                                               const float* __restrict__ Bl,   // [N,R]
                                               unsigned short* __restrict__ Wm, int Kd) {
  __shared__ float sBm[64 * 64];
  __shared__ float sAl[64 * 68];
  const int tid = threadIdx.x;
  const int n0 = blockIdx.y * 64, k0 = blockIdx.x * 64;
#pragma unroll
  for (int it = 0; it < 4; ++it) {
    int e = it * 1024 + tid * 4;
    int row = e >> 6, col = e & 63;
    *(fx4*)&sBm[row * 64 + col] = *(const fx4*)(Bl + (size_t)(n0 + row) * 64 + col);
    *(fx4*)&sAl[row * 68 + col] = *(const fx4*)(Al + (size_t)row * Kd + k0 + col);
  }
  __syncthreads();
  const int lane = tid & 63, wave = tid >> 6;
  for (int nn = 0; nn < 16; ++nn) {
    int n = wave * 16 + nn;
    float a = 0.f;
#pragma unroll
    for (int r = 0; r < 64; ++r) a += sBm[n * 64 + r] * sAl[r * 68 + lane];
    size_t gi = (size_t)(n0 + n) * Kd + k0 + lane;
    Wm[gi] = f2bf(W[gi] + 0.25f * a);
  }
}

// ---------------------------------------------------------------------------
// Main GEMM: C[M,N] = A_bf16[M,K] @ W[N,K]^T
// Grid: (x = M-tiles [fast], y = N-tiles)  -> weight tile shared by
// consecutive blocks, streamed from HBM ~once.
// WB16: W bf16 via global_load_lds (XOR swizzle). !WB16: W f32 reg-staged.
// EPI 0: store f32 C      EPI 2: outF = C + aux (residual)
// ---------------------------------------------------------------------------
template <int EPI, bool WB16>
__global__ __launch_bounds__(256, 2) void k_gemm(const unsigned short* __restrict__ A,
                                                 const unsigned short* __restrict__ Wb,
                                                 const float* __restrict__ Wf,
                                                 float* __restrict__ outF,
                                                 const float* __restrict__ aux,
                                                 int M, int N, int K) {
  __shared__ unsigned short sA[128 * 64];
  __shared__ unsigned short sB[128 * 72];
  const int tid = threadIdx.x;
  const int wave = tid >> 6, lane = tid & 63;
  const int m0 = blockIdx.x * 128, n0 = blockIdx.y * 128;
  const int wr = wave >> 1, wc = wave & 1;
  const int l15 = lane & 15, l4 = lane >> 4;

  fx4 acc[4][4];
#pragma unroll
  for (int i = 0; i < 4; ++i)
#pragma unroll
    for (int j = 0; j < 4; ++j) acc[i][j] = (fx4){0.f, 0.f, 0.f, 0.f};

  const int nsteps = K >> 6;
  const int arow = tid >> 3;
  const int acol = (((tid & 7) ^ (arow & 7)) << 3);
  const int brow = tid >> 4;
  const int bcol = (tid & 15) << 2;

  for (int t = 0; t < nsteps; ++t) {
    const int kb = t << 6;
#pragma unroll
    for (int i = 0; i < 4; ++i) {
      const unsigned short* gp = A + (size_t)(m0 + i * 32 + arow) * K + kb + acol;
      unsigned short* lp = sA + i * 2048 + wave * 512;
      __builtin_amdgcn_global_load_lds(
          (const __attribute__((address_space(1))) unsigned int*)gp,
          (__attribute__((address_space(3))) unsigned int*)lp, 16, 0, 0);
    }
    if (WB16) {
#pragma unroll
      for (int i = 0; i < 4; ++i) {
        const unsigned short* gp = Wb + (size_t)(n0 + i * 32 + arow) * K + kb + acol;
        unsigned short* lp = sB + i * 2048 + wave * 512;
        __builtin_amdgcn_global_load_lds(
            (const __attribute__((address_space(1))) unsigned int*)gp,
            (__attribute__((address_space(3))) unsigned int*)lp, 16, 0, 0);
      }
    } else {
#pragma unroll
      for (int j = 0; j < 8; ++j) {
        int row = j * 16 + brow;
        fx4 v = *(const fx4*)(Wf + (size_t)(n0 + row) * K + kb + bcol);
        u16x4t pk;
        pk.x = f2bf(v[0]); pk.y = f2bf(v[1]); pk.z = f2bf(v[2]); pk.w = f2bf(v[3]);
        *(u16x4t*)&sB[row * 72 + bcol] = pk;
      }
    }
    __syncthreads();
#pragma unroll
    for (int ks = 0; ks < 2; ++ks) {
      s16x8 af[4], bfr[4];
#pragma unroll
      for (int i = 0; i < 4; ++i) {
        int row = wr * 64 + i * 16 + l15;
        int cid = (((ks * 4) + l4) ^ (row & 7)) << 3;
        af[i] = *(const s16x8*)&sA[row * 64 + cid];
      }
#pragma unroll
      for (int j = 0; j < 4; ++j) {
        int row = wc * 64 + j * 16 + l15;
        if (WB16) {
          int cid = (((ks * 4) + l4) ^ (row & 7)) << 3;
          bfr[j] = *(const s16x8*)&sB[row * 64 + cid];
        } else {
          bfr[j] = *(const s16x8*)&sB[row * 72 + ks * 32 + (l4 << 3)];
        }
      }
#pragma unroll
      for (int i = 0; i < 4; ++i)
#pragma unroll
        for (int j = 0; j < 4; ++j)
          acc[i][j] = __builtin_amdgcn_mfma_f32_16x16x32_bf16(af[i], bfr[j], acc[i][j], 0, 0, 0);
    }
    __syncthreads();
  }

  const int r0 = m0 + wr * 64 + (l4 << 2);
  const int c0 = n0 + wc * 64 + l15;
#pragma unroll
  for (int i = 0; i < 4; ++i)
#pragma unroll
    for (int j = 0; j < 4; ++j)
#pragma unroll
      for (int r = 0; r < 4; ++r) {
        size_t idx = (size_t)(r0 + i * 16 + r) * N + (c0 + j * 16);
        float v = acc[i][j][r];
        if (EPI == 0) outF[idx] = v;
        else          outF[idx] = v + aux[idx];
      }
}

// ---------------------------------------------------------------------------
// Fused gate+up GEMM: out = bf16( silu(A@Wg^T) * (A@Wu^T) )
// Grid: (x = M-tiles [fast], y = F-tiles). Wg/Wu f32 reg-staged -> bf16 LDS.
// ---------------------------------------------------------------------------
__global__ __launch_bounds__(256, 2) void k_gemm_gu(const unsigned short* __restrict__ A,
                                                    const float* __restrict__ Wg,
                                                    const float* __restrict__ Wu,
                                                    unsigned short* __restrict__ outB,
                                                    int M, int N, int K) {
  __shared__ unsigned short sA[128 * 64];
  __shared__ unsigned short sG[128 * 72];
  __shared__ unsigned short sU[128 * 72];
  const int tid = threadIdx.x;
  const int wave = tid >> 6, lane = tid & 63;
  const int m0 = blockIdx.x * 128, n0 = blockIdx.y * 128;
  const int wr = wave >> 1, wc = wave & 1;
  const int l15 = lane & 15, l4 = lane >> 4;

  fx4 accg[4][4], accu[4][4];
#pragma unroll
  for (int i = 0; i < 4; ++i)
#pragma unroll
    for (int j = 0; j < 4; ++j) {
      accg[i][j] = (fx4){0.f, 0.f, 0.f, 0.f};
      accu[i][j] = (fx4){0.f, 0.f, 0.f, 0.f};
    }

  const int nsteps = K >> 6;
  const int arow = tid >> 3;
  const int acol = (((tid & 7) ^ (arow & 7)) << 3);
  const int brow = tid >> 4;
  const int bcol = (tid & 15) << 2;

  for (int t = 0; t < nsteps; ++t) {
    const int kb = t << 6;
#pragma unroll
    for (int i = 0; i < 4; ++i) {
      const unsigned short* gp = A + (size_t)(m0 + i * 32 + arow) * K + kb + acol;
      unsigned short* lp = sA + i * 2048 + wave * 512;
      __builtin_amdgcn_global_load_lds(
          (const __attribute__((address_space(1))) unsigned int*)gp,
          (__attribute__((address_space(3))) unsigned int*)lp, 16, 0, 0);
    }
#pragma unroll
    for (int j = 0; j < 8; ++j) {
      int row = j * 16 + brow;
      fx4 vg = *(const fx4*)(Wg + (size_t)(n0 + row) * K + kb + bcol);
      u16x4t pg;
      pg.x = f2bf(vg[0]); pg.y = f2bf(vg[1]); pg.z = f2bf(vg[2]); pg.w = f2bf(vg[3]);
      *(u16x4t*)&sG[row * 72 + bcol] = pg;
      fx4 vu = *(const fx4*)(Wu + (size_t)(n0 + row) * K + kb + bcol);
      u16x4t pu;
      pu.x = f2bf(vu[0]); pu.y = f2bf(vu[1]); pu.z = f2bf(vu[2]); pu.w = f2bf(vu[3]);
      *(u16x4t*)&sU[row * 72 + bcol] = pu;
    }
    __syncthreads();
#pragma unroll
    for (int ks = 0; ks < 2; ++ks) {
      s16x8 af[4], bg[4], bu[4];
#pragma unroll
      for (int i = 0; i < 4; ++i) {
        int row = wr * 64 + i * 16 + l15;
        int cid = (((ks * 4) + l4) ^ (row & 7)) << 3;
        af[i] = *(const s16x8*)&sA[row * 64 + cid];
      }
#pragma unroll
      for (int j = 0; j < 4; ++j) {
        int row = wc * 64 + j * 16 + l15;
        bg[j] = *(const s16x8*)&sG[row * 72 + ks * 32 + (l4 << 3)];
        bu[j] = *(const s16x8*)&sU[row * 72 + ks * 32 + (l4 << 3)];
      }
#pragma unroll
      for (int i = 0; i < 4; ++i)
#pragma unroll
        for (int j = 0; j < 4; ++j) {
          accg[i][j] = __builtin_amdgcn_mfma_f32_16x16x32_bf16(af[i], bg[j], accg[i][j], 0, 0, 0);
          accu[i][j] = __builtin_amdgcn_mfma_f32_16x16x32_bf16(af[i], bu[j], accu[i][j], 0, 0, 0);
        }
    }
    __syncthreads();
  }

  const int r0 = m0 + wr * 64 + (l4 << 2);
  const int c0 = n0 + wc * 64 + l15;
#pragma unroll
  for (int i = 0; i < 4; ++i)
#pragma unroll
    for (int j = 0; j < 4; ++j)
#pragma unroll
      for (int r = 0; r < 4; ++r) {
        size_t idx = (size_t)(r0 + i * 16 + r) * N + (c0 + j * 16);
        float g = accg[i][j][r];
        outB[idx] = f2bf(accu[i][j][r] * g / (1.f + __expf(-g)));
      }
}

// ---------------------------------------------------------------------------
// RoPE tables
// ---------------------------------------------------------------------------
__global__ void k_ropetab(float* __restrict__ cosT, float* __restrict__ sinT) {
  int idx = blockIdx.x * 256 + threadIdx.x;
  int s = idx >> 6, d = idx & 63;
  float inv = powf(10000.f, -(float)d * (1.f / 64.f));
  float f = (float)s * inv;
  cosT[idx] = cosf(f);
  sinT[idx] = sinf(f);
}

// ---------------------------------------------------------------------------
// RoPE + cvt + head-transpose
// ---------------------------------------------------------------------------
__global__ __launch_bounds__(256) void k_rope(const float* __restrict__ P,
                                              const float* __restrict__ cosT,
                                              const float* __restrict__ sinT,
                                              unsigned short* __restrict__ out) {
  const int tok = blockIdx.x, tid = threadIdx.x;
  const int b = tok >> 10, s = tok & 1023;
  const int h = tid >> 3, d0 = (tid & 7) * 8;
  const float* src = P + (size_t)tok * D_ + h * HD_;
  fx4 a0 = *(const fx4*)(src + d0);
  fx4 a1 = *(const fx4*)(src + d0 + 4);
  fx4 b0 = *(const fx4*)(src + 64 + d0);
  fx4 b1 = *(const fx4*)(src + 64 + d0 + 4);
  fx4 c0 = *(const fx4*)(cosT + s * 64 + d0);
  fx4 c1 = *(const fx4*)(cosT + s * 64 + d0 + 4);
  fx4 s0 = *(const fx4*)(sinT + s * 64 + d0);
  fx4 s1 = *(const fx4*)(sinT + s * 64 + d0 + 4);
  unsigned short* dst = out + ((size_t)(b * H_ + h) * SS + s) * HD_;
  u16x4t lo0, lo1, hi0, hi1;
#pragma unroll
  for (int j = 0; j < 4; ++j) {
    lo0[j] = f2bf(a0[j] * c0[j] - b0[j] * s0[j]);
    lo1[j] = f2bf(a1[j] * c1[j] - b1[j] * s1[j]);
    hi0[j] = f2bf(b0[j] * c0[j] + a0[j] * s0[j]);
    hi1[j] = f2bf(b1[j] * c1[j] + a1[j] * s1[j]);
  }
  *(u16x4t*)(dst + d0) = lo0;
  *(u16x4t*)(dst + d0 + 4) = lo1;
  *(u16x4t*)(dst + 64 + d0) = hi0;
  *(u16x4t*)(dst + 64 + d0 + 4) = hi1;
}

// ---------------------------------------------------------------------------
// Flash attention
// ---------------------------------------------------------------------------
__global__ __launch_bounds__(256, 2) void k_attn(const unsigned short* __restrict__ Q,
                                                 const unsigned short* __restrict__ Kb,
                                                 const float* __restrict__ Pv,
                                                 const int* __restrict__ am,
                                                 unsigned short* __restrict__ O) {
  __shared__ unsigned short sK[32 * 136];
  __shared__ unsigned short sV[128 * 40];
  __shared__ unsigned short sP[4 * 16 * 40];
  const int tid = threadIdx.x, wave = tid >> 6, lane = tid & 63;
  const int bh = blockIdx.y, b = bh >> 5, h = bh & 31;
  const int qt = blockIdx.x;
  const float scale = 0.08838834764831845f;
  const int l15 = lane & 15, l4 = lane >> 4;

  s16x8 qf[4];
  {
    const unsigned short* qp = Q + ((size_t)bh * SS + qt * 64 + wave * 16 + l15) * HD_;
#pragma unroll
    for (int ks = 0; ks < 4; ++ks) qf[ks] = *(const s16x8*)(qp + ks * 32 + l4 * 8);
  }
  fx4 oacc[8];
#pragma unroll
  for (int nf = 0; nf < 8; ++nf) oacc[nf] = (fx4){0.f, 0.f, 0.f, 0.f};
  float mrun[4] = {-1e30f, -1e30f, -1e30f, -1e30f};
  float lrun[4] = {0.f, 0.f, 0.f, 0.f};

  const int ntiles = (qt + 1) * 2;
  for (int kt = 0; kt < ntiles; ++kt) {
    const int k0 = kt * 32;
    __syncthreads();
    {
      int row = tid >> 3, cbase = (tid & 7) * 8;
      const unsigned short* kp = Kb + ((size_t)bh * SS + k0 + row) * HD_;
      *(fx4*)&sK[row * 136 + cbase]      = *(const fx4*)(kp + cbase);
      *(fx4*)&sK[row * 136 + cbase + 64] = *(const fx4*)(kp + cbase + 64);
    }
    {
#pragma unroll
      for (int it = 0; it < 4; ++it) {
        int key = it * 8 + (tid >> 5), hd0 = (tid & 31) * 4;
        fx4 v = *(const fx4*)(Pv + ((size_t)b * SS + k0 + key) * D_ + h * HD_ + hd0);
        sV[(hd0 + 0) * 40 + key] = f2bf(v[0]);
        sV[(hd0 + 1) * 40 + key] = f2bf(v[1]);
        sV[(hd0 + 2) * 40 + key] = f2bf(v[2]);
        sV[(hd0 + 3) * 40 + key] = f2bf(v[3]);
      }
    }
    __syncthreads();
    if (k0 <= qt * 64 + wave * 16 + 15) {
      fx4 s0 = (fx4){0.f, 0.f, 0.f, 0.f};
      fx4 s1 = (fx4){0.f, 0.f, 0.f, 0.f};
#pragma unroll
      for (int ks = 0; ks < 4; ++ks) {
        s16x8 kf0 = *(const s16x8*)&sK[l15 * 136 + ks * 32 + l4 * 8];
        s16x8 kf1 = *(const s16x8*)&sK[(16 + l15) * 136 + ks * 32 + l4 * 8];
        s0 = __builtin_amdgcn_mfma_f32_16x16x32_bf16(qf[ks], kf0, s0, 0, 0, 0);
        s1 = __builtin_amdgcn_mfma_f32_16x16x32_bf16(qf[ks], kf1, s1, 0, 0, 0);
      }
      float p[8], corr[4];
#pragma unroll
      for (int r = 0; r < 4; ++r) {
        int qr = qt * 64 + wave * 16 + l4 * 4 + r;
        int key0 = k0 + l15, key1 = key0 + 16;
        float b0 = (key0 <= qr && am[b * SS + key0] != 0) ? 0.f : -1e9f;
        float b1 = (key1 <= qr && am[b * SS + key1] != 0) ? 0.f : -1e9f;
        p[r]     = s0[r] * scale + b0;
        p[4 + r] = s1[r] * scale + b1;
        float m = fmaxf(p[r], p[4 + r]);
        m = fmaxf(m, __shfl_xor(m, 1));
        m = fmaxf(m, __shfl_xor(m, 2));
        m = fmaxf(m, __shfl_xor(m, 4));
        m = fmaxf(m, __shfl_xor(m, 8));
        float mn = fmaxf(mrun[r], m);
        corr[r] = __expf(mrun[r] - mn);
        mrun[r] = mn;
        p[r]     = __expf(p[r] - mn);
        p[4 + r] = __expf(p[4 + r] - mn);
        float rs = p[r] + p[4 + r];
        rs += __shfl_xor(rs, 1);
        rs += __shfl_xor(rs, 2);
        rs += __shfl_xor(rs, 4);
        rs += __shfl_xor(rs, 8);
        lrun[r] = lrun[r] * corr[r] + rs;
      }
#pragma unroll
      for (int nf = 0; nf < 8; ++nf) {
        oacc[nf][0] *= corr[0];
        oacc[nf][1] *= corr[1];
        oacc[nf][2] *= corr[2];
        oacc[nf][3] *= corr[3];
      }
      unsigned short* pp = sP + wave * 640;
#pragma unroll
      for (int r = 0; r < 4; ++r) {
        int row = l4 * 4 + r;
        pp[row * 40 + l15]      = f2bf(p[r]);
        pp[row * 40 + 16 + l15] = f2bf(p[4 + r]);
      }
      s16x8 pa = *(const s16x8*)&pp[l15 * 40 + l4 * 8];
#pragma unroll
      for (int nf = 0; nf < 8; ++nf) {
        s16x8 vf = *(const s16x8*)&sV[(nf * 16 + l15) * 40 + l4 * 8];
        oacc[nf] = __builtin_amdgcn_mfma_f32_16x16x32_bf16(pa, vf, oacc[nf], 0, 0, 0);
      }
    }
  }
  const size_t obase = (size_t)b * SS * D_ + h * HD_;
#pragma unroll
  for (int nf = 0; nf < 8; ++nf)
#pragma unroll
    for (int r = 0; r < 4; ++r) {
      int qr = qt * 64 + wave * 16 + l4 * 4 + r;
      O[obase + (size_t)qr * D_ + nf * 16 + l15] = f2bf(oacc[nf][r] / lrun[r]);
    }
}

// ---------------------------------------------------------------------------
// Final RMSNorm + classifier
// ---------------------------------------------------------------------------
__global__ __launch_bounds__(256) void k_final(const float* __restrict__ xf,
                                               const float* __restrict__ fw,
                                               const float* __restrict__ cW,
                                               const float* __restrict__ cb,
                                               float* __restrict__ out) {
  const int b = blockIdx.x, tid = threadIdx.x;
  const float* xr = xf + (size_t)b * SS * D_;
  __shared__ float red[4];
  fx4 v[4];
  float ss = 0.f;
#pragma unroll
  for (int i = 0; i < 4; ++i) {
    v[i] = *(const fx4*)(xr + i * 1024 + tid * 4);
    ss += v[i][0]*v[i][0] + v[i][1]*v[i][1] + v[i][2]*v[i][2] + v[i][3]*v[i][3];
  }
#pragma unroll
  for (int off = 32; off > 0; off >>= 1) ss += __shfl_down(ss, off);
  if ((tid & 63) == 0) red[tid >> 6] = ss;
  __syncthreads();
  const float sc = rsqrtf((red[0] + red[1] + red[2] + red[3]) * (1.f / D_) + EPS_);
  for (int c = 0; c < 3; ++c) {
    float d = 0.f;
#pragma unroll
    for (int i = 0; i < 4; ++i) {
      fx4 fv = *(const fx4*)(fw + i * 1024 + tid * 4);
      fx4 cw = *(const fx4*)(cW + (size_t)c * D_ + i * 1024 + tid * 4);
#pragma unroll
      for (int j = 0; j < 4; ++j) d += v[i][j] * sc * fv[j] * cw[j];
    }
#pragma unroll
    for (int off = 32; off > 0; off >>= 1) d += __shfl_down(d, off);
    __syncthreads();
    if ((tid & 63) == 0) red[tid >> 6] = d;
    __syncthreads();
    if (tid == 0) out[b * 3 + c] = red[0] + red[1] + red[2] + red[3] + cb[c];
  }
}

// ---------------------------------------------------------------------------
extern "C" void kernel_launch(void* const* d_in, const int* in_sizes, int n_in,
                              void* d_out, int out_size, void* d_ws, size_t ws_size,
                              hipStream_t stream) {
  const int*   ids = (const int*)d_in[0];
  const int*   am  = (const int*)d_in[1];
  const float* emb = (const float*)d_in[2];
  const float* Wq  = (const float*)d_in[3];
  const float* Wk  = (const float*)d_in[4];
  const float* Wv  = (const float*)d_in[5];
  const float* Wo  = (const float*)d_in[6];
  const float* Aq  = (const float*)d_in[7];
  const float* Bq  = (const float*)d_in[8];
  const float* Ak  = (const float*)d_in[9];
  const float* Bk  = (const float*)d_in[10];
  const float* Av  = (const float*)d_in[11];
  const float* Bv  = (const float*)d_in[12];
  const float* Ao  = (const float*)d_in[13];
  const float* Bo  = (const float*)d_in[14];
  const float* Wg  = (const float*)d_in[15];
  const float* Wu  = (const float*)d_in[16];
  const float* Wd  = (const float*)d_in[17];
  const float* anw = (const float*)d_in[18];
  const float* mnw = (const float*)d_in[19];
  const float* fnw = (const float*)d_in[20];
  const float* cW  = (const float*)d_in[21];
  const float* cb  = (const float*)d_in[22];
  float* out = (float*)d_out;

  char* w = (char*)d_ws;
  float* xf = (float*)w;            w += (size_t)TOK * D_ * 4;
  float* P  = (float*)w;            w += (size_t)TOK * D_ * 4;
  unsigned short* gact = (unsigned short*)w; w += (size_t)TOK * F_ * 2;
  unsigned short* hb = (unsigned short*)w;   w += (size_t)TOK * D_ * 2;
  unsigned short* qb = (unsigned short*)w;   w += (size_t)TOK * D_ * 2;
  unsigned short* kb = (unsigned short*)w;   w += (size_t)TOK * D_ * 2;
  unsigned short* ob = (unsigned short*)w;   w += (size_t)TOK * D_ * 2;
  unsigned short* Wm = (unsigned short*)w;   w += (size_t)D_ * D_ * 2;
  float* cosT = (float*)w;          w += (size_t)SS * 64 * 4;
  float* sinT = (float*)w;          w += (size_t)SS * 64 * 4;
  if ((size_t)(w - (char*)d_ws) > ws_size) return;

  k_ropetab<<<256, 256, 0, stream>>>(cosT, sinT);
  k_embed<<<TOK, 256, 0, stream>>>(ids, emb, xf);

  dim3 gProj(TOK / 128, D_ / 128);    // (16,32)  x = M-tiles (fast)
  dim3 gGU(TOK / 128, F_ / 128);      // (16,86)
  dim3 gMerge(D_ / 64, D_ / 64);
  dim3 gAttn(SS / 64, BB * H_);

  for (int l = 0; l < L_; ++l) {
    const size_t oDD = (size_t)l * D_ * D_;
    const size_t oRD = (size_t)l * R_ * D_;
    const size_t oDR = (size_t)l * D_ * R_;
    const size_t oFD = (size_t)l * F_ * D_;

    k_rmsnorm<<<TOK, 256, 0, stream>>>(xf, anw + (size_t)l * D_, hb);
    // Q
    k_merge<<<gMerge, 256, 0, stream>>>(Wq + oDD, Aq + oRD, Bq + oDR, Wm, D_);
    k_gemm<0, true><<<gProj, 256, 0, stream>>>(hb, Wm, nullptr, P, nullptr, TOK, D_, D_);
    k_rope<<<TOK, 256, 0, stream>>>(P, cosT, sinT, qb);
    // K
    k_merge<<<gMerge, 256, 0, stream>>>(Wk + oDD, Ak + oRD, Bk + oDR, Wm, D_);
    k_gemm<0, true><<<gProj, 256, 0, stream>>>(hb, Wm, nullptr, P, nullptr, TOK, D_, D_);
    k_rope<<<TOK, 256, 0, stream>>>(P, cosT, sinT, kb);
    // V (stays f32 in P)
    k_merge<<<gMerge, 256, 0, stream>>>(Wv + oDD, Av + oRD, Bv + oDR, Wm, D_);
    k_gemm<0, true><<<gProj, 256, 0, stream>>>(hb, Wm, nullptr, P, nullptr, TOK, D_, D_);
    // attention
    k_attn<<<gAttn, 256, 0, stream>>>(qb, kb, P, am, ob);
    // O projection + residual
    k_merge<<<gMerge, 256, 0, stream>>>(Wo + oDD, Ao + oRD, Bo + oDR, Wm, D_);
    k_gemm<2, true><<<gProj, 256, 0, stream>>>(ob, Wm, nullptr, xf, xf, TOK, D_, D_);
    // MLP: fused gate+up, then down + residual
    k_rmsnorm<<<TOK, 256, 0, stream>>>(xf, mnw + (size_t)l * D_, hb);
    k_gemm_gu<<<gGU, 256, 0, stream>>>(hb, Wg + oFD, Wu + oFD, gact, TOK, F_, D_);
    k_gemm<2, false><<<gProj, 256, 0, stream>>>(gact, nullptr, Wd + oFD, xf, xf, TOK, D_, F_);
  }

  k_final<<<BB, 256, 0, stream>>>(xf, fnw, cW, cb, out);
  (void)in_sizes; (void)n_in; (void)out_size;
}

// Round 5
// 3385.613 us; speedup vs baseline: 1.6576x; 1.6576x over previous
//
#include <hip/hip_runtime.h>
#include <cstdint>
#include <cstddef>

#define D_   4096
#define H_   32
#define HD_  128
#define F_   11008
#define L_   2
#define R_   64
#define BB   2
#define SS   1024
#define TOK  (BB*SS)
#define EPS_ 1e-5f

typedef __attribute__((ext_vector_type(8))) short          s16x8;
typedef __attribute__((ext_vector_type(4))) float          fx4;
typedef __attribute__((ext_vector_type(4))) unsigned short u16x4t;
typedef __attribute__((ext_vector_type(8))) unsigned short u16x8t;

__device__ __forceinline__ unsigned short f2bf(float f) {
  union { float f; unsigned u; } x; x.f = f;
  unsigned r = (x.u + 0x7FFFu + ((x.u >> 16) & 1u)) >> 16;
  return (unsigned short)r;
}
__device__ __forceinline__ float b2f(unsigned short h) {
  union { unsigned u; float f; } x; x.u = ((unsigned)h) << 16;
  return x.f;
}

// ---------------------------------------------------------------------------
// Embedding gather
// ---------------------------------------------------------------------------
__global__ void k_embed(const int* __restrict__ ids, const float* __restrict__ emb,
                        float* __restrict__ x) {
  const int tok = blockIdx.x, tid = threadIdx.x;
  const int id = ids[tok];
  const float* s = emb + (size_t)id * D_;
  float* d = x + (size_t)tok * D_;
#pragma unroll
  for (int i = 0; i < 4; ++i)
    *(fx4*)(d + i * 1024 + tid * 4) = *(const fx4*)(s + i * 1024 + tid * 4);
}

// ---------------------------------------------------------------------------
// f32 -> bf16 streaming convert (weights): one HBM pass, bf16 stays L3-hot
// ---------------------------------------------------------------------------
__global__ __launch_bounds__(256) void k_cvt(const float* __restrict__ src,
                                             unsigned short* __restrict__ dst, int n) {
  const int stride = gridDim.x * 256 * 8;
  for (int i = (blockIdx.x * 256 + threadIdx.x) * 8; i < n; i += stride) {
    fx4 a = *(const fx4*)(src + i);
    fx4 b = *(const fx4*)(src + i + 4);
    u16x8t p;
    p[0] = f2bf(a[0]); p[1] = f2bf(a[1]); p[2] = f2bf(a[2]); p[3] = f2bf(a[3]);
    p[4] = f2bf(b[0]); p[5] = f2bf(b[1]); p[6] = f2bf(b[2]); p[7] = f2bf(b[3]);
    *(u16x8t*)(dst + i) = p;
  }
}

// ---------------------------------------------------------------------------
// RMSNorm row -> bf16
// ---------------------------------------------------------------------------
__global__ __launch_bounds__(256) void k_rmsnorm(const float* __restrict__ x,
                                                 const float* __restrict__ w,
                                                 unsigned short* __restrict__ out) {
  const int row = blockIdx.x, tid = threadIdx.x;
  const float* xr = x + (size_t)row * D_;
  fx4 v[4];
  float ss = 0.f;
#pragma unroll
  for (int i = 0; i < 4; ++i) {
    v[i] = *(const fx4*)(xr + i * 1024 + tid * 4);
    ss += v[i][0]*v[i][0] + v[i][1]*v[i][1] + v[i][2]*v[i][2] + v[i][3]*v[i][3];
  }
#pragma unroll
  for (int off = 32; off > 0; off >>= 1) ss += __shfl_down(ss, off);
  __shared__ float red[4];
  if ((tid & 63) == 0) red[tid >> 6] = ss;
  __syncthreads();
  const float sc = rsqrtf((red[0] + red[1] + red[2] + red[3]) * (1.f / D_) + EPS_);
  unsigned short* orow = out + (size_t)row * D_;
#pragma unroll
  for (int i = 0; i < 4; ++i) {
    fx4 wv = *(const fx4*)(w + i * 1024 + tid * 4);
    u16x4t pk;
    pk.x = f2bf(v[i][0] * sc * wv[0]);
    pk.y = f2bf(v[i][1] * sc * wv[1]);
    pk.z = f2bf(v[i][2] * sc * wv[2]);
    pk.w = f2bf(v[i][3] * sc * wv[3]);
    *(u16x4t*)(orow + i * 1024 + tid * 4) = pk;
  }
}

// ---------------------------------------------------------------------------
// LoRA-merged weight: Wm[n,k] = bf16(W[n,k] + 0.25 * sum_r Bl[n,r]*Al[r,k])
// ---------------------------------------------------------------------------
__global__ __launch_bounds__(256) void k_merge(const float* __restrict__ W,
                                               const float* __restrict__ Al,   // [R,Kd]
                                               const float* __restrict__ Bl,   // [N,R]
                                               unsigned short* __restrict__ Wm, int Kd) {
  __shared__ float sBm[64 * 64];
  __shared__ float sAl[64 * 68];
  const int tid = threadIdx.x;
  const int n0 = blockIdx.y * 64, k0 = blockIdx.x * 64;
#pragma unroll
  for (int it = 0; it < 4; ++it) {
    int e = it * 1024 + tid * 4;
    int row = e >> 6, col = e & 63;
    *(fx4*)&sBm[row * 64 + col] = *(const fx4*)(Bl + (size_t)(n0 + row) * 64 + col);
    *(fx4*)&sAl[row * 68 + col] = *(const fx4*)(Al + (size_t)row * Kd + k0 + col);
  }
  __syncthreads();
  const int lane = tid & 63, wave = tid >> 6;
  for (int nn = 0; nn < 16; ++nn) {
    int n = wave * 16 + nn;
    float a = 0.f;
#pragma unroll
    for (int r = 0; r < 64; ++r) a += sBm[n * 64 + r] * sAl[r * 68 + lane];
    size_t gi = (size_t)(n0 + n) * Kd + k0 + lane;
    Wm[gi] = f2bf(W[gi] + 0.25f * a);
  }
}

// ---------------------------------------------------------------------------
// Main GEMM: C[M,N] = A_bf16[M,K] @ W_bf16[N,K]^T  (global_load_lds both sides,
// XOR-swizzled LDS). Grid: (x = N-tiles, y = M-tiles).
// EPI 0: outF = C                 EPI 2: outF = C + auxF   (residual)
// EPI 3: outB = bf16(silu(C))     EPI 4: outB = bf16(C * b2f(auxB)) in-place ok
// ---------------------------------------------------------------------------
template <int EPI>
__global__ __launch_bounds__(256, 4) void k_gemm(const unsigned short* __restrict__ A,
                                                 const unsigned short* __restrict__ Wb,
                                                 float* __restrict__ outF,
                                                 unsigned short* __restrict__ outB,
                                                 const float* __restrict__ auxF,
                                                 const unsigned short* __restrict__ auxB,
                                                 int M, int N, int K) {
  __shared__ unsigned short sA[128 * 64];
  __shared__ unsigned short sB[128 * 64];
  const int tid = threadIdx.x;
  const int wave = tid >> 6, lane = tid & 63;
  const int m0 = blockIdx.y * 128, n0 = blockIdx.x * 128;
  const int wr = wave >> 1, wc = wave & 1;
  const int l15 = lane & 15, l4 = lane >> 4;

  fx4 acc[4][4];
#pragma unroll
  for (int i = 0; i < 4; ++i)
#pragma unroll
    for (int j = 0; j < 4; ++j) acc[i][j] = (fx4){0.f, 0.f, 0.f, 0.f};

  const int nsteps = K >> 6;
  const int arow = tid >> 3;                        // 0..31 within 32-row group
  const int acol = (((tid & 7) ^ (arow & 7)) << 3); // swizzled elem col

  for (int t = 0; t < nsteps; ++t) {
    const int kb = t << 6;
#pragma unroll
    for (int i = 0; i < 4; ++i) {
      const unsigned short* gp = A + (size_t)(m0 + i * 32 + arow) * K + kb + acol;
      unsigned short* lp = sA + i * 2048 + wave * 512;
      __builtin_amdgcn_global_load_lds(
          (const __attribute__((address_space(1))) unsigned int*)gp,
          (__attribute__((address_space(3))) unsigned int*)lp, 16, 0, 0);
    }
#pragma unroll
    for (int i = 0; i < 4; ++i) {
      const unsigned short* gp = Wb + (size_t)(n0 + i * 32 + arow) * K + kb + acol;
      unsigned short* lp = sB + i * 2048 + wave * 512;
      __builtin_amdgcn_global_load_lds(
          (const __attribute__((address_space(1))) unsigned int*)gp,
          (__attribute__((address_space(3))) unsigned int*)lp, 16, 0, 0);
    }
    __syncthreads();
#pragma unroll
    for (int ks = 0; ks < 2; ++ks) {
      s16x8 af[4], bfr[4];
#pragma unroll
      for (int i = 0; i < 4; ++i) {
        int row = wr * 64 + i * 16 + l15;
        int cid = (((ks * 4) + l4) ^ (row & 7)) << 3;
        af[i] = *(const s16x8*)&sA[row * 64 + cid];
      }
#pragma unroll
      for (int j = 0; j < 4; ++j) {
        int row = wc * 64 + j * 16 + l15;
        int cid = (((ks * 4) + l4) ^ (row & 7)) << 3;
        bfr[j] = *(const s16x8*)&sB[row * 64 + cid];
      }
#pragma unroll
      for (int i = 0; i < 4; ++i)
#pragma unroll
        for (int j = 0; j < 4; ++j)
          acc[i][j] = __builtin_amdgcn_mfma_f32_16x16x32_bf16(af[i], bfr[j], acc[i][j], 0, 0, 0);
    }
    __syncthreads();
  }

  const int r0 = m0 + wr * 64 + (l4 << 2);
  const int c0 = n0 + wc * 64 + l15;
#pragma unroll
  for (int i = 0; i < 4; ++i)
#pragma unroll
    for (int j = 0; j < 4; ++j)
#pragma unroll
      for (int r = 0; r < 4; ++r) {
        size_t idx = (size_t)(r0 + i * 16 + r) * N + (c0 + j * 16);
        float v = acc[i][j][r];
        if (EPI == 0) {
          outF[idx] = v;
        } else if (EPI == 2) {
          outF[idx] = v + auxF[idx];
        } else if (EPI == 3) {
          outB[idx] = f2bf(v / (1.f + __expf(-v)));
        } else { // EPI == 4
          outB[idx] = f2bf(v * b2f(auxB[idx]));
        }
      }
}

// ---------------------------------------------------------------------------
// RoPE tables
// ---------------------------------------------------------------------------
__global__ void k_ropetab(float* __restrict__ cosT, float* __restrict__ sinT) {
  int idx = blockIdx.x * 256 + threadIdx.x;
  int s = idx >> 6, d = idx & 63;
  float inv = powf(10000.f, -(float)d * (1.f / 64.f));
  float f = (float)s * inv;
  cosT[idx] = cosf(f);
  sinT[idx] = sinf(f);
}

// ---------------------------------------------------------------------------
// RoPE + cvt + head-transpose
// ---------------------------------------------------------------------------
__global__ __launch_bounds__(256) void k_rope(const float* __restrict__ P,
                                              const float* __restrict__ cosT,
                                              const float* __restrict__ sinT,
                                              unsigned short* __restrict__ out) {
  const int tok = blockIdx.x, tid = threadIdx.x;
  const int b = tok >> 10, s = tok & 1023;
  const int h = tid >> 3, d0 = (tid & 7) * 8;
  const float* src = P + (size_t)tok * D_ + h * HD_;
  fx4 a0 = *(const fx4*)(src + d0);
  fx4 a1 = *(const fx4*)(src + d0 + 4);
  fx4 b0 = *(const fx4*)(src + 64 + d0);
  fx4 b1 = *(const fx4*)(src + 64 + d0 + 4);
  fx4 c0 = *(const fx4*)(cosT + s * 64 + d0);
  fx4 c1 = *(const fx4*)(cosT + s * 64 + d0 + 4);
  fx4 s0 = *(const fx4*)(sinT + s * 64 + d0);
  fx4 s1 = *(const fx4*)(sinT + s * 64 + d0 + 4);
  unsigned short* dst = out + ((size_t)(b * H_ + h) * SS + s) * HD_;
  u16x4t lo0, lo1, hi0, hi1;
#pragma unroll
  for (int j = 0; j < 4; ++j) {
    lo0[j] = f2bf(a0[j] * c0[j] - b0[j] * s0[j]);
    lo1[j] = f2bf(a1[j] * c1[j] - b1[j] * s1[j]);
    hi0[j] = f2bf(b0[j] * c0[j] + a0[j] * s0[j]);
    hi1[j] = f2bf(b1[j] * c1[j] + a1[j] * s1[j]);
  }
  *(u16x4t*)(dst + d0) = lo0;
  *(u16x4t*)(dst + d0 + 4) = lo1;
  *(u16x4t*)(dst + 64 + d0) = hi0;
  *(u16x4t*)(dst + 64 + d0 + 4) = hi1;
}

// ---------------------------------------------------------------------------
// Flash attention
// ---------------------------------------------------------------------------
__global__ __launch_bounds__(256, 2) void k_attn(const unsigned short* __restrict__ Q,
                                                 const unsigned short* __restrict__ Kb,
                                                 const float* __restrict__ Pv,
                                                 const int* __restrict__ am,
                                                 unsigned short* __restrict__ O) {
  __shared__ unsigned short sK[32 * 136];
  __shared__ unsigned short sV[128 * 40];
  __shared__ unsigned short sP[4 * 16 * 40];
  const int tid = threadIdx.x, wave = tid >> 6, lane = tid & 63;
  const int bh = blockIdx.y, b = bh >> 5, h = bh & 31;
  const int qt = blockIdx.x;
  const float scale = 0.08838834764831845f;
  const int l15 = lane & 15, l4 = lane >> 4;

  s16x8 qf[4];
  {
    const unsigned short* qp = Q + ((size_t)bh * SS + qt * 64 + wave * 16 + l15) * HD_;
#pragma unroll
    for (int ks = 0; ks < 4; ++ks) qf[ks] = *(const s16x8*)(qp + ks * 32 + l4 * 8);
  }
  fx4 oacc[8];
#pragma unroll
  for (int nf = 0; nf < 8; ++nf) oacc[nf] = (fx4){0.f, 0.f, 0.f, 0.f};
  float mrun[4] = {-1e30f, -1e30f, -1e30f, -1e30f};
  float lrun[4] = {0.f, 0.f, 0.f, 0.f};

  const int ntiles = (qt + 1) * 2;
  for (int kt = 0; kt < ntiles; ++kt) {
    const int k0 = kt * 32;
    __syncthreads();
    {
      int row = tid >> 3, cbase = (tid & 7) * 8;
      const unsigned short* kp = Kb + ((size_t)bh * SS + k0 + row) * HD_;
      *(fx4*)&sK[row * 136 + cbase]      = *(const fx4*)(kp + cbase);
      *(fx4*)&sK[row * 136 + cbase + 64] = *(const fx4*)(kp + cbase + 64);
    }
    {
#pragma unroll
      for (int it = 0; it < 4; ++it) {
        int key = it * 8 + (tid >> 5), hd0 = (tid & 31) * 4;
        fx4 v = *(const fx4*)(Pv + ((size_t)b * SS + k0 + key) * D_ + h * HD_ + hd0);
        sV[(hd0 + 0) * 40 + key] = f2bf(v[0]);
        sV[(hd0 + 1) * 40 + key] = f2bf(v[1]);
        sV[(hd0 + 2) * 40 + key] = f2bf(v[2]);
        sV[(hd0 + 3) * 40 + key] = f2bf(v[3]);
      }
    }
    __syncthreads();
    if (k0 <= qt * 64 + wave * 16 + 15) {
      fx4 s0 = (fx4){0.f, 0.f, 0.f, 0.f};
      fx4 s1 = (fx4){0.f, 0.f, 0.f, 0.f};
#pragma unroll
      for (int ks = 0; ks < 4; ++ks) {
        s16x8 kf0 = *(const s16x8*)&sK[l15 * 136 + ks * 32 + l4 * 8];
        s16x8 kf1 = *(const s16x8*)&sK[(16 + l15) * 136 + ks * 32 + l4 * 8];
        s0 = __builtin_amdgcn_mfma_f32_16x16x32_bf16(qf[ks], kf0, s0, 0, 0, 0);
        s1 = __builtin_amdgcn_mfma_f32_16x16x32_bf16(qf[ks], kf1, s1, 0, 0, 0);
      }
      float p[8], corr[4];
#pragma unroll
      for (int r = 0; r < 4; ++r) {
        int qr = qt * 64 + wave * 16 + l4 * 4 + r;
        int key0 = k0 + l15, key1 = key0 + 16;
        float b0 = (key0 <= qr && am[b * SS + key0] != 0) ? 0.f : -1e9f;
        float b1 = (key1 <= qr && am[b * SS + key1] != 0) ? 0.f : -1e9f;
        p[r]     = s0[r] * scale + b0;
        p[4 + r] = s1[r] * scale + b1;
        float m = fmaxf(p[r], p[4 + r]);
        m = fmaxf(m, __shfl_xor(m, 1));
        m = fmaxf(m, __shfl_xor(m, 2));
        m = fmaxf(m, __shfl_xor(m, 4));
        m = fmaxf(m, __shfl_xor(m, 8));
        float mn = fmaxf(mrun[r], m);
        corr[r] = __expf(mrun[r] - mn);
        mrun[r] = mn;
        p[r]     = __expf(p[r] - mn);
        p[4 + r] = __expf(p[4 + r] - mn);
        float rs = p[r] + p[4 + r];
        rs += __shfl_xor(rs, 1);
        rs += __shfl_xor(rs, 2);
        rs += __shfl_xor(rs, 4);
        rs += __shfl_xor(rs, 8);
        lrun[r] = lrun[r] * corr[r] + rs;
      }
#pragma unroll
      for (int nf = 0; nf < 8; ++nf) {
        oacc[nf][0] *= corr[0];
        oacc[nf][1] *= corr[1];
        oacc[nf][2] *= corr[2];
        oacc[nf][3] *= corr[3];
      }
      unsigned short* pp = sP + wave * 640;
#pragma unroll
      for (int r = 0; r < 4; ++r) {
        int row = l4 * 4 + r;
        pp[row * 40 + l15]      = f2bf(p[r]);
        pp[row * 40 + 16 + l15] = f2bf(p[4 + r]);
      }
      s16x8 pa = *(const s16x8*)&pp[l15 * 40 + l4 * 8];
#pragma unroll
      for (int nf = 0; nf < 8; ++nf) {
        s16x8 vf = *(const s16x8*)&sV[(nf * 16 + l15) * 40 + l4 * 8];
        oacc[nf] = __builtin_amdgcn_mfma_f32_16x16x32_bf16(pa, vf, oacc[nf], 0, 0, 0);
      }
    }
  }
  const size_t obase = (size_t)b * SS * D_ + h * HD_;
#pragma unroll
  for (int nf = 0; nf < 8; ++nf)
#pragma unroll
    for (int r = 0; r < 4; ++r) {
      int qr = qt * 64 + wave * 16 + l4 * 4 + r;
      O[obase + (size_t)qr * D_ + nf * 16 + l15] = f2bf(oacc[nf][r] / lrun[r]);
    }
}

// ---------------------------------------------------------------------------
// Final RMSNorm + classifier
// ---------------------------------------------------------------------------
__global__ __launch_bounds__(256) void k_final(const float* __restrict__ xf,
                                               const float* __restrict__ fw,
                                               const float* __restrict__ cW,
                                               const float* __restrict__ cb,
                                               float* __restrict__ out) {
  const int b = blockIdx.x, tid = threadIdx.x;
  const float* xr = xf + (size_t)b * SS * D_;
  __shared__ float red[4];
  fx4 v[4];
  float ss = 0.f;
#pragma unroll
  for (int i = 0; i < 4; ++i) {
    v[i] = *(const fx4*)(xr + i * 1024 + tid * 4);
    ss += v[i][0]*v[i][0] + v[i][1]*v[i][1] + v[i][2]*v[i][2] + v[i][3]*v[i][3];
  }
#pragma unroll
  for (int off = 32; off > 0; off >>= 1) ss += __shfl_down(ss, off);
  if ((tid & 63) == 0) red[tid >> 6] = ss;
  __syncthreads();
  const float sc = rsqrtf((red[0] + red[1] + red[2] + red[3]) * (1.f / D_) + EPS_);
  for (int c = 0; c < 3; ++c) {
    float d = 0.f;
#pragma unroll
    for (int i = 0; i < 4; ++i) {
      fx4 fv = *(const fx4*)(fw + i * 1024 + tid * 4);
      fx4 cw = *(const fx4*)(cW + (size_t)c * D_ + i * 1024 + tid * 4);
#pragma unroll
      for (int j = 0; j < 4; ++j) d += v[i][j] * sc * fv[j] * cw[j];
    }
#pragma unroll
    for (int off = 32; off > 0; off >>= 1) d += __shfl_down(d, off);
    __syncthreads();
    if ((tid & 63) == 0) red[tid >> 6] = d;
    __syncthreads();
    if (tid == 0) out[b * 3 + c] = red[0] + red[1] + red[2] + red[3] + cb[c];
  }
}

// ---------------------------------------------------------------------------
extern "C" void kernel_launch(void* const* d_in, const int* in_sizes, int n_in,
                              void* d_out, int out_size, void* d_ws, size_t ws_size,
                              hipStream_t stream) {
  const int*   ids = (const int*)d_in[0];
  const int*   am  = (const int*)d_in[1];
  const float* emb = (const float*)d_in[2];
  const float* Wq  = (const float*)d_in[3];
  const float* Wk  = (const float*)d_in[4];
  const float* Wv  = (const float*)d_in[5];
  const float* Wo  = (const float*)d_in[6];
  const float* Aq  = (const float*)d_in[7];
  const float* Bq  = (const float*)d_in[8];
  const float* Ak  = (const float*)d_in[9];
  const float* Bk  = (const float*)d_in[10];
  const float* Av  = (const float*)d_in[11];
  const float* Bv  = (const float*)d_in[12];
  const float* Ao  = (const float*)d_in[13];
  const float* Bo  = (const float*)d_in[14];
  const float* Wg  = (const float*)d_in[15];
  const float* Wu  = (const float*)d_in[16];
  const float* Wd  = (const float*)d_in[17];
  const float* anw = (const float*)d_in[18];
  const float* mnw = (const float*)d_in[19];
  const float* fnw = (const float*)d_in[20];
  const float* cW  = (const float*)d_in[21];
  const float* cb  = (const float*)d_in[22];
  float* out = (float*)d_out;

  char* w = (char*)d_ws;
  float* xf = (float*)w;            w += (size_t)TOK * D_ * 4;
  float* P  = (float*)w;            w += (size_t)TOK * D_ * 4;
  unsigned short* gact = (unsigned short*)w; w += (size_t)TOK * F_ * 2;
  unsigned short* hb = (unsigned short*)w;   w += (size_t)TOK * D_ * 2;
  unsigned short* qb = (unsigned short*)w;   w += (size_t)TOK * D_ * 2;
  unsigned short* kb = (unsigned short*)w;   w += (size_t)TOK * D_ * 2;
  unsigned short* ob = (unsigned short*)w;   w += (size_t)TOK * D_ * 2;
  unsigned short* Wm = (unsigned short*)w;   w += (size_t)D_ * D_ * 2;
  unsigned short* Wc = (unsigned short*)w;   w += (size_t)F_ * D_ * 2;
  float* cosT = (float*)w;          w += (size_t)SS * 64 * 4;
  float* sinT = (float*)w;          w += (size_t)SS * 64 * 4;
  if ((size_t)(w - (char*)d_ws) > ws_size) return;

  k_ropetab<<<256, 256, 0, stream>>>(cosT, sinT);
  k_embed<<<TOK, 256, 0, stream>>>(ids, emb, xf);

  dim3 gProj(D_ / 128, TOK / 128);    // (32,16)  x = N-tiles
  dim3 gMlp(F_ / 128, TOK / 128);     // (86,16)
  dim3 gMerge(D_ / 64, D_ / 64);
  dim3 gAttn(SS / 64, BB * H_);
  const int CVT_BLK = 2048;

  for (int l = 0; l < L_; ++l) {
    const size_t oDD = (size_t)l * D_ * D_;
    const size_t oRD = (size_t)l * R_ * D_;
    const size_t oDR = (size_t)l * D_ * R_;
    const size_t oFD = (size_t)l * F_ * D_;

    k_rmsnorm<<<TOK, 256, 0, stream>>>(xf, anw + (size_t)l * D_, hb);
    // Q
    k_merge<<<gMerge, 256, 0, stream>>>(Wq + oDD, Aq + oRD, Bq + oDR, Wm, D_);
    k_gemm<0><<<gProj, 256, 0, stream>>>(hb, Wm, P, nullptr, nullptr, nullptr, TOK, D_, D_);
    k_rope<<<TOK, 256, 0, stream>>>(P, cosT, sinT, qb);
    // K
    k_merge<<<gMerge, 256, 0, stream>>>(Wk + oDD, Ak + oRD, Bk + oDR, Wm, D_);
    k_gemm<0><<<gProj, 256, 0, stream>>>(hb, Wm, P, nullptr, nullptr, nullptr, TOK, D_, D_);
    k_rope<<<TOK, 256, 0, stream>>>(P, cosT, sinT, kb);
    // V (stays f32 in P)
    k_merge<<<gMerge, 256, 0, stream>>>(Wv + oDD, Av + oRD, Bv + oDR, Wm, D_);
    k_gemm<0><<<gProj, 256, 0, stream>>>(hb, Wm, P, nullptr, nullptr, nullptr, TOK, D_, D_);
    // attention
    k_attn<<<gAttn, 256, 0, stream>>>(qb, kb, P, am, ob);
    // O projection + residual
    k_merge<<<gMerge, 256, 0, stream>>>(Wo + oDD, Ao + oRD, Bo + oDR, Wm, D_);
    k_gemm<2><<<gProj, 256, 0, stream>>>(ob, Wm, xf, nullptr, xf, nullptr, TOK, D_, D_);
    // MLP: bf16-convert each weight once (L3-hot), then bf16 GEMMs
    k_rmsnorm<<<TOK, 256, 0, stream>>>(xf, mnw + (size_t)l * D_, hb);
    k_cvt<<<CVT_BLK, 256, 0, stream>>>(Wg + oFD, Wc, F_ * D_);
    k_gemm<3><<<gMlp, 256, 0, stream>>>(hb, Wc, nullptr, gact, nullptr, nullptr, TOK, F_, D_);
    k_cvt<<<CVT_BLK, 256, 0, stream>>>(Wu + oFD, Wc, F_ * D_);
    k_gemm<4><<<gMlp, 256, 0, stream>>>(hb, Wc, nullptr, gact, nullptr, gact, TOK, F_, D_);
    k_cvt<<<CVT_BLK, 256, 0, stream>>>(Wd + oFD, Wc, D_ * F_);
    k_gemm<2><<<gProj, 256, 0, stream>>>(gact, Wc, xf, nullptr, xf, nullptr, TOK, D_, F_);
  }

  k_final<<<BB, 256, 0, stream>>>(xf, fnw, cW, cb, out);
  (void)in_sizes; (void)n_in; (void)out_size;
}